// Round 4
// baseline (106.321 us; speedup 1.0000x reference)
//
#include <hip/hip_runtime.h>
#include <hip/hip_bf16.h>
#include <stdint.h>

#define NB 2048
#define NU 512
#define NL 32
#define NH 64

typedef float  f4    __attribute__((ext_vector_type(4)));
typedef uint32_t u32x4 __attribute__((ext_vector_type(4)));
typedef short  s16x8 __attribute__((ext_vector_type(8)));

__device__ __forceinline__ f4 mfma16(u32x4 a, u32x4 b, f4 c) {
    return __builtin_amdgcn_mfma_f32_16x16x32_bf16(
        __builtin_bit_cast(s16x8, a), __builtin_bit_cast(s16x8, b), c, 0, 0, 0);
}

// truncation split of pair (we,wo): hi exact (bit-AND), lo = rounded remainder.
__device__ __forceinline__ void splitpk(float we, float wo, uint32_t& hp, uint32_t& lp) {
    uint32_t ue = __float_as_uint(we), uo = __float_as_uint(wo);
    hp = __builtin_amdgcn_perm(uo, ue, 0x07060302u);
    float le = we - __uint_as_float(ue & 0xFFFF0000u);
    float lo = wo - __uint_as_float(uo & 0xFFFF0000u);
    lp = __builtin_amdgcn_perm(__float_as_uint(lo) + 0x8000u,
                               __float_as_uint(le) + 0x8000u, 0x07060302u);
}

// round-to-nearest(ish) single-bf16 pack of a pair
__device__ __forceinline__ uint32_t rpk(float e, float o) {
    return __builtin_amdgcn_perm(__float_as_uint(o) + 0x8000u,
                                 __float_as_uint(e) + 0x8000u, 0x07060302u);
}

// ---------------------------------------------------------------- encoder ---
__global__ __launch_bounds__(256)
void enc_kernel(const float* __restrict__ x,
                const float* __restrict__ We1, const float* __restrict__ be1,
                const float* __restrict__ We2, const float* __restrict__ be2,
                const float* __restrict__ We3, const float* __restrict__ be3,
                const float* __restrict__ We4, const float* __restrict__ be4,
                float* __restrict__ z)
{
    const int RE = 8;
    __shared__ float xs[RE][512];
    __shared__ float ws[128 * 64];
    __shared__ float h[RE][NH];
    __shared__ float h2s[RE][NH];

    const int t  = threadIdx.x;
    const int r0 = blockIdx.x * RE;

    {
        const f4* xv  = (const f4*)(x + (size_t)r0 * 512);
        f4*       xsv = (f4*)&xs[0][0];
        for (int i = t; i < RE * 512 / 4; i += 256) xsv[i] = xv[i];
    }

    const int j = t & 63;
    const int w = t >> 6;

    float acc0 = be1[j], acc1 = be1[j];
    for (int kc = 0; kc < 512; kc += 128) {
        __syncthreads();
        const f4* wv  = (const f4*)(We1 + (size_t)kc * 64);
        f4*       wsv = (f4*)ws;
        for (int i = t; i < 128 * 64 / 4; i += 256) wsv[i] = wv[i];
        __syncthreads();
        #pragma unroll 8
        for (int k = 0; k < 128; ++k) {
            float wval = ws[k * 64 + j];
            acc0 = fmaf(xs[w][kc + k],     wval, acc0);
            acc1 = fmaf(xs[w + 4][kc + k], wval, acc1);
        }
    }
    acc0 = fmaxf(acc0, 0.f); acc1 = fmaxf(acc1, 0.f);
    __syncthreads();
    h[w][j] = acc0; h[w + 4][j] = acc1;
    __syncthreads();

    acc0 = be2[j]; acc1 = be2[j];
    #pragma unroll
    for (int k = 0; k < 64; ++k) {
        float wval = We2[k * 64 + j];
        acc0 = fmaf(h[w][k],     wval, acc0);
        acc1 = fmaf(h[w + 4][k], wval, acc1);
    }
    acc0 = fmaxf(acc0, 0.f); acc1 = fmaxf(acc1, 0.f);
    h2s[w][j] = acc0; h2s[w + 4][j] = acc1;
    __syncthreads();

    acc0 = be3[j]; acc1 = be3[j];
    #pragma unroll
    for (int k = 0; k < 64; ++k) {
        float wval = We3[k * 64 + j];
        acc0 = fmaf(h2s[w][k],     wval, acc0);
        acc1 = fmaf(h2s[w + 4][k], wval, acc1);
    }
    acc0 = fmaxf(acc0, 0.f); acc1 = fmaxf(acc1, 0.f);
    h[w][j] = acc0; h[w + 4][j] = acc1;
    __syncthreads();

    const int j4  = t & 31;
    const int row = t >> 5;
    float acc = be4[j4];
    #pragma unroll
    for (int k = 0; k < 64; ++k)
        acc = fmaf(h[row][k], We4[k * 32 + j4], acc);
    z[(size_t)r0 * 32 + t] = acc;
}

// ---------------------------------------------------------------- decoder ---
// 512 blocks (1/unit), 4 waves x 16 private rows, 32 iters.
// launch_bounds(256,1): allow ~256 VGPRs so split weight frags stay resident.
// Block->unit swizzle keeps each 64B out-line within one XCD (no false share).
__global__ __launch_bounds__(256, 1)
void dec_kernel(const float* __restrict__ z,
                const float* __restrict__ Wd1, const float* __restrict__ bd1,
                const float* __restrict__ Wd2, const float* __restrict__ bd2,
                const float* __restrict__ Wd3, const float* __restrict__ bd3,
                const float* __restrict__ Wd4, const float* __restrict__ bd4,
                float* __restrict__ out)
{
    __shared__ float w1[NL * NH];     // 8 KB
    __shared__ float w2[NH * NH];     // 16 KB
    __shared__ float w3[NH * NH];     // 16 KB
    __shared__ float bsh[3][NH];
    __shared__ float w4s[NH];

    // unit swizzle: u-groups of 16 (one 64B out-line) all land on one XCD
    // (XCD = bid % 8 heuristic; wrong mapping only costs perf, not correctness)
    const int bid = blockIdx.x;
    const int u = ((bid & 7) << 4) | (((bid >> 3) & 3) << 7) | (bid >> 5);
    const int t = threadIdx.x;

    // stage weights (coalesced f4)
    {
        const f4* s1 = (const f4*)(Wd1 + (size_t)u * NL * NH);
        f4* d1 = (f4*)w1;
        for (int i = t; i < NL * NH / 4; i += 256) d1[i] = s1[i];
        const f4* s2 = (const f4*)(Wd2 + (size_t)u * NH * NH);
        f4* d2 = (f4*)w2;
        for (int i = t; i < NH * NH / 4; i += 256) d2[i] = s2[i];
        const f4* s3 = (const f4*)(Wd3 + (size_t)u * NH * NH);
        f4* d3 = (f4*)w3;
        for (int i = t; i < NH * NH / 4; i += 256) d3[i] = s3[i];
        if (t < NH) {
            bsh[0][t] = bd1[(size_t)u * NH + t];
            bsh[1][t] = bd2[(size_t)u * NH + t];
            bsh[2][t] = bd3[(size_t)u * NH + t];
            w4s[t]    = Wd4[(size_t)u * NH + t];
        }
    }
    __syncthreads();

    const int w  = t >> 6;          // wave 0..3
    const int lr = t & 15;          // batch-row lane
    const int lg = (t & 63) >> 4;   // lane group 0..3
    const bool hi32 = (t & 32) != 0;
    const float b4 = bd4[u];

    // ---- register A-fragments (W^T), truncation-split hi/lo ----
    u32x4 a1h[4], a1l[4];
    u32x4 a2h[4][2], a2l[4][2], a3h[4][2], a3l[4][2];
    #pragma unroll
    for (int mt = 0; mt < 4; ++mt) {
        const int c = lr + 16 * mt;
        #pragma unroll
        for (int i = 0; i < 4; ++i) {
            uint32_t hp, lp;
            splitpk(w1[(lg * 8 + 2 * i) * NH + c], w1[(lg * 8 + 2 * i + 1) * NH + c], hp, lp);
            a1h[mt][i] = hp; a1l[mt][i] = lp;
        }
        #pragma unroll
        for (int ks = 0; ks < 2; ++ks) {
            #pragma unroll
            for (int i = 0; i < 4; ++i) {
                const int k = ks * 32 + lg * 8 + 2 * i;
                uint32_t hp, lp;
                splitpk(w2[k * NH + c], w2[(k + 1) * NH + c], hp, lp);
                a2h[mt][ks][i] = hp; a2l[mt][ks][i] = lp;
                splitpk(w3[k * NH + c], w3[(k + 1) * NH + c], hp, lp);
                a3h[mt][ks][i] = hp; a3l[mt][ks][i] = lp;
            }
        }
    }

    // biases packed bf16 pairs (exact here: zeros)
    uint32_t bpk1[4][2], bpk2[4][2], bpk3[4][2];
    #pragma unroll
    for (int mt = 0; mt < 4; ++mt) {
        const int c = 16 * mt + lg * 4;
        bpk1[mt][0] = rpk(bsh[0][c], bsh[0][c + 1]);
        bpk1[mt][1] = rpk(bsh[0][c + 2], bsh[0][c + 3]);
        bpk2[mt][0] = rpk(bsh[1][c], bsh[1][c + 1]);
        bpk2[mt][1] = rpk(bsh[1][c + 2], bsh[1][c + 3]);
        bpk3[mt][0] = rpk(bsh[2][c], bsh[2][c + 1]);
        bpk3[mt][1] = rpk(bsh[2][c + 2], bsh[2][c + 3]);
    }

    // bpermute byte indices: source lane = lr + 32*(lg&1) + 16*(i>>1)
    const int idxA = (lr + 32 * (lg & 1)) << 2;
    const int idxB = idxA + 64;

    const int rl = w * 16 + lr;     // block-local row of this lane

    // z prefetch double-buffer
    f4 zc0 = *(const f4*)(z + (size_t)rl * NL + lg * 8);
    f4 zc1 = *(const f4*)(z + (size_t)rl * NL + lg * 8 + 4);

    for (int it = 0; it < 32; ++it) {
        const int row = it * 64 + rl;
        const int rnext = ((it + 1) & 31) * 64 + rl;
        f4 zn0 = *(const f4*)(z + (size_t)rnext * NL + lg * 8);
        f4 zn1 = *(const f4*)(z + (size_t)rnext * NL + lg * 8 + 4);

        // ---- L1 B: split z (3-term keeps z exact) ----
        u32x4 bh, bl;
        {
            uint32_t hp, lp;
            splitpk(zc0[0], zc0[1], hp, lp); bh[0] = hp; bl[0] = lp;
            splitpk(zc0[2], zc0[3], hp, lp); bh[1] = hp; bl[1] = lp;
            splitpk(zc1[0], zc1[1], hp, lp); bh[2] = hp; bl[2] = lp;
            splitpk(zc1[2], zc1[3], hp, lp); bh[3] = hp; bl[3] = lp;
        }

        f4 acc[4];
        #pragma unroll
        for (int mt = 0; mt < 4; ++mt) {
            acc[mt][0] = __uint_as_float(bpk1[mt][0] << 16);
            acc[mt][1] = __uint_as_float(bpk1[mt][0] & 0xFFFF0000u);
            acc[mt][2] = __uint_as_float(bpk1[mt][1] << 16);
            acc[mt][3] = __uint_as_float(bpk1[mt][1] & 0xFFFF0000u);
            acc[mt] = mfma16(a1h[mt], bh, acc[mt]);
            acc[mt] = mfma16(a1l[mt], bh, acc[mt]);
            acc[mt] = mfma16(a1h[mt], bl, acc[mt]);
        }

        // relu + pack h1 (single bf16)
        uint32_t pk[4][2];
        #pragma unroll
        for (int mt = 0; mt < 4; ++mt) {
            pk[mt][0] = rpk(fmaxf(acc[mt][0], 0.f), fmaxf(acc[mt][1], 0.f));
            pk[mt][1] = rpk(fmaxf(acc[mt][2], 0.f), fmaxf(acc[mt][3], 0.f));
        }

        // ---- L2 ----
        #pragma unroll
        for (int mt = 0; mt < 4; ++mt) {
            acc[mt][0] = __uint_as_float(bpk2[mt][0] << 16);
            acc[mt][1] = __uint_as_float(bpk2[mt][0] & 0xFFFF0000u);
            acc[mt][2] = __uint_as_float(bpk2[mt][1] << 16);
            acc[mt][3] = __uint_as_float(bpk2[mt][1] & 0xFFFF0000u);
        }
        #pragma unroll
        for (int ks = 0; ks < 2; ++ks) {
            u32x4 bf;
            {
                int s0 = __builtin_amdgcn_ds_bpermute(idxA, (int)pk[2 * ks + 0][0]);
                int s1 = __builtin_amdgcn_ds_bpermute(idxA, (int)pk[2 * ks + 1][0]);
                bf[0] = (uint32_t)(hi32 ? s1 : s0);
                int s2 = __builtin_amdgcn_ds_bpermute(idxA, (int)pk[2 * ks + 0][1]);
                int s3 = __builtin_amdgcn_ds_bpermute(idxA, (int)pk[2 * ks + 1][1]);
                bf[1] = (uint32_t)(hi32 ? s3 : s2);
                int s4 = __builtin_amdgcn_ds_bpermute(idxB, (int)pk[2 * ks + 0][0]);
                int s5 = __builtin_amdgcn_ds_bpermute(idxB, (int)pk[2 * ks + 1][0]);
                bf[2] = (uint32_t)(hi32 ? s5 : s4);
                int s6 = __builtin_amdgcn_ds_bpermute(idxB, (int)pk[2 * ks + 0][1]);
                int s7 = __builtin_amdgcn_ds_bpermute(idxB, (int)pk[2 * ks + 1][1]);
                bf[3] = (uint32_t)(hi32 ? s7 : s6);
            }
            #pragma unroll
            for (int mt = 0; mt < 4; ++mt) {
                acc[mt] = mfma16(a2h[mt][ks], bf, acc[mt]);
                acc[mt] = mfma16(a2l[mt][ks], bf, acc[mt]);
            }
        }

        // relu + pack h2
        uint32_t pk2[4][2];
        #pragma unroll
        for (int mt = 0; mt < 4; ++mt) {
            pk2[mt][0] = rpk(fmaxf(acc[mt][0], 0.f), fmaxf(acc[mt][1], 0.f));
            pk2[mt][1] = rpk(fmaxf(acc[mt][2], 0.f), fmaxf(acc[mt][3], 0.f));
        }

        // ---- L3 ----
        #pragma unroll
        for (int mt = 0; mt < 4; ++mt) {
            acc[mt][0] = __uint_as_float(bpk3[mt][0] << 16);
            acc[mt][1] = __uint_as_float(bpk3[mt][0] & 0xFFFF0000u);
            acc[mt][2] = __uint_as_float(bpk3[mt][1] << 16);
            acc[mt][3] = __uint_as_float(bpk3[mt][1] & 0xFFFF0000u);
        }
        #pragma unroll
        for (int ks = 0; ks < 2; ++ks) {
            u32x4 bf;
            {
                int s0 = __builtin_amdgcn_ds_bpermute(idxA, (int)pk2[2 * ks + 0][0]);
                int s1 = __builtin_amdgcn_ds_bpermute(idxA, (int)pk2[2 * ks + 1][0]);
                bf[0] = (uint32_t)(hi32 ? s1 : s0);
                int s2 = __builtin_amdgcn_ds_bpermute(idxA, (int)pk2[2 * ks + 0][1]);
                int s3 = __builtin_amdgcn_ds_bpermute(idxA, (int)pk2[2 * ks + 1][1]);
                bf[1] = (uint32_t)(hi32 ? s3 : s2);
                int s4 = __builtin_amdgcn_ds_bpermute(idxB, (int)pk2[2 * ks + 0][0]);
                int s5 = __builtin_amdgcn_ds_bpermute(idxB, (int)pk2[2 * ks + 1][0]);
                bf[2] = (uint32_t)(hi32 ? s5 : s4);
                int s6 = __builtin_amdgcn_ds_bpermute(idxB, (int)pk2[2 * ks + 0][1]);
                int s7 = __builtin_amdgcn_ds_bpermute(idxB, (int)pk2[2 * ks + 1][1]);
                bf[3] = (uint32_t)(hi32 ? s7 : s6);
            }
            #pragma unroll
            for (int mt = 0; mt < 4; ++mt) {
                acc[mt] = mfma16(a3h[mt][ks], bf, acc[mt]);
                acc[mt] = mfma16(a3l[mt][ks], bf, acc[mt]);
            }
        }

        // ---- L4: fp32 dot with wd4 (h3 never rounded) ----
        float part = 0.f;
        #pragma unroll
        for (int mt = 0; mt < 4; ++mt) {
            f4 wv = *(const f4*)&w4s[16 * mt + lg * 4];
            part = fmaf(fmaxf(acc[mt][0], 0.f), wv[0], part);
            part = fmaf(fmaxf(acc[mt][1], 0.f), wv[1], part);
            part = fmaf(fmaxf(acc[mt][2], 0.f), wv[2], part);
            part = fmaf(fmaxf(acc[mt][3], 0.f), wv[3], part);
        }
        part += __shfl_xor(part, 16);
        part += __shfl_xor(part, 32);
        if ((t & 48) == 0)
            out[(size_t)row * NU + u] = part + b4;

        zc0 = zn0; zc1 = zn1;
    }
}

// ----------------------------------------------------------------- launch ---
extern "C" void kernel_launch(void* const* d_in, const int* in_sizes, int n_in,
                              void* d_out, int out_size, void* d_ws, size_t ws_size,
                              hipStream_t stream)
{
    const float* x   = (const float*)d_in[0];
    const float* We1 = (const float*)d_in[1];
    const float* be1 = (const float*)d_in[2];
    const float* We2 = (const float*)d_in[3];
    const float* be2 = (const float*)d_in[4];
    const float* We3 = (const float*)d_in[5];
    const float* be3 = (const float*)d_in[6];
    const float* We4 = (const float*)d_in[7];
    const float* be4 = (const float*)d_in[8];
    const float* Wd1 = (const float*)d_in[9];
    const float* bd1 = (const float*)d_in[10];
    const float* Wd2 = (const float*)d_in[11];
    const float* bd2 = (const float*)d_in[12];
    const float* Wd3 = (const float*)d_in[13];
    const float* bd3 = (const float*)d_in[14];
    const float* Wd4 = (const float*)d_in[15];
    const float* bd4 = (const float*)d_in[16];
    float* out = (float*)d_out;

    float* zbuf = (float*)d_ws;   // 256 KB scratch

    enc_kernel<<<NB / 8, 256, 0, stream>>>(x, We1, be1, We2, be2, We3, be3,
                                           We4, be4, zbuf);
    dec_kernel<<<NU, 256, 0, stream>>>(zbuf, Wd1, bd1, Wd2, bd2,
                                       Wd3, bd3, Wd4, bd4, out);
}

// Round 5
// 63.505 us; speedup vs baseline: 1.6742x; 1.6742x over previous
//
#include <hip/hip_runtime.h>
#include <hip/hip_bf16.h>
#include <hip/hip_fp16.h>
#include <stdint.h>

#define NB 2048
#define NU 512
#define NL 32
#define NH 64

typedef float    f4    __attribute__((ext_vector_type(4)));
typedef uint32_t u32x4 __attribute__((ext_vector_type(4)));
typedef _Float16 h8    __attribute__((ext_vector_type(8)));

__device__ __forceinline__ f4 mfma16h(u32x4 a, u32x4 b, f4 c) {
    return __builtin_amdgcn_mfma_f32_16x16x32_f16(
        __builtin_bit_cast(h8, a), __builtin_bit_cast(h8, b), c, 0, 0, 0);
}

// RNE fp16 pack of a pair (weights, init-time only)
__device__ __forceinline__ uint32_t pk_rne(float e, float o) {
    __half he = __float2half_rn(e), ho = __float2half_rn(o);
    return (uint32_t)__half_as_ushort(he) | ((uint32_t)__half_as_ushort(ho) << 16);
}

// RTZ fp16 pack (activations, 1 VALU op)
__device__ __forceinline__ uint32_t pk_rtz(float e, float o) {
    return __builtin_bit_cast(uint32_t, __builtin_amdgcn_cvt_pkrtz(e, o));
}

// bf16 pack of a pair (bias storage; 1-op unpack via shift/and)
__device__ __forceinline__ uint32_t rpk(float e, float o) {
    return __builtin_amdgcn_perm(__float_as_uint(o) + 0x8000u,
                                 __float_as_uint(e) + 0x8000u, 0x07060302u);
}

// act exchange: 4x16-lane-group block transpose via permlane swaps.
// (A,B) = (pk[2ks][w], pk[2ks+1][w]) -> (bf[0+w], bf[2+w])
// Verified identical mapping to the proven ds_bpermute version:
//   out0 = [A.j0, A.j2, B.j0, B.j2], out1 = [A.j1, A.j3, B.j1, B.j3]
__device__ __forceinline__ void xch(uint32_t A, uint32_t B,
                                    uint32_t& o0, uint32_t& o1) {
    asm volatile("v_permlane32_swap_b32 %0, %1" : "+v"(A), "+v"(B));
    asm volatile("v_permlane16_swap_b32 %0, %1" : "+v"(A), "+v"(B));
    o0 = A; o1 = B;
}

// ---------------------------------------------------------------- encoder ---
__global__ __launch_bounds__(256)
void enc_kernel(const float* __restrict__ x,
                const float* __restrict__ We1, const float* __restrict__ be1,
                const float* __restrict__ We2, const float* __restrict__ be2,
                const float* __restrict__ We3, const float* __restrict__ be3,
                const float* __restrict__ We4, const float* __restrict__ be4,
                float* __restrict__ z)
{
    const int RE = 8;
    __shared__ float xs[RE][512];
    __shared__ float ws[128 * 64];
    __shared__ float h[RE][NH];
    __shared__ float h2s[RE][NH];

    const int t  = threadIdx.x;
    const int r0 = blockIdx.x * RE;

    {
        const f4* xv  = (const f4*)(x + (size_t)r0 * 512);
        f4*       xsv = (f4*)&xs[0][0];
        for (int i = t; i < RE * 512 / 4; i += 256) xsv[i] = xv[i];
    }

    const int j = t & 63;
    const int w = t >> 6;

    float acc0 = be1[j], acc1 = be1[j];
    for (int kc = 0; kc < 512; kc += 128) {
        __syncthreads();
        const f4* wv  = (const f4*)(We1 + (size_t)kc * 64);
        f4*       wsv = (f4*)ws;
        for (int i = t; i < 128 * 64 / 4; i += 256) wsv[i] = wv[i];
        __syncthreads();
        #pragma unroll 8
        for (int k = 0; k < 128; ++k) {
            float wval = ws[k * 64 + j];
            acc0 = fmaf(xs[w][kc + k],     wval, acc0);
            acc1 = fmaf(xs[w + 4][kc + k], wval, acc1);
        }
    }
    acc0 = fmaxf(acc0, 0.f); acc1 = fmaxf(acc1, 0.f);
    __syncthreads();
    h[w][j] = acc0; h[w + 4][j] = acc1;
    __syncthreads();

    acc0 = be2[j]; acc1 = be2[j];
    #pragma unroll
    for (int k = 0; k < 64; ++k) {
        float wval = We2[k * 64 + j];
        acc0 = fmaf(h[w][k],     wval, acc0);
        acc1 = fmaf(h[w + 4][k], wval, acc1);
    }
    acc0 = fmaxf(acc0, 0.f); acc1 = fmaxf(acc1, 0.f);
    h2s[w][j] = acc0; h2s[w + 4][j] = acc1;
    __syncthreads();

    acc0 = be3[j]; acc1 = be3[j];
    #pragma unroll
    for (int k = 0; k < 64; ++k) {
        float wval = We3[k * 64 + j];
        acc0 = fmaf(h2s[w][k],     wval, acc0);
        acc1 = fmaf(h2s[w + 4][k], wval, acc1);
    }
    acc0 = fmaxf(acc0, 0.f); acc1 = fmaxf(acc1, 0.f);
    h[w][j] = acc0; h[w + 4][j] = acc1;
    __syncthreads();

    const int j4  = t & 31;
    const int row = t >> 5;
    float acc = be4[j4];
    #pragma unroll
    for (int k = 0; k < 64; ++k)
        acc = fmaf(h[row][k], We4[k * 32 + j4], acc);
    z[(size_t)r0 * 32 + t] = acc;
}

// ---------------------------------------------------------------- decoder ---
// 512 blocks (1/unit), 4 waves x 16 rows, 32 iters.
// fp16 single-term MFMA (frags 80 regs, resident); permlane-swap exchange
// (zero LDS traffic in the loop); unit swizzle vs out false-sharing.
__global__ __launch_bounds__(256, 1)
void dec_kernel(const float* __restrict__ z,
                const float* __restrict__ Wd1, const float* __restrict__ bd1,
                const float* __restrict__ Wd2, const float* __restrict__ bd2,
                const float* __restrict__ Wd3, const float* __restrict__ bd3,
                const float* __restrict__ Wd4, const float* __restrict__ bd4,
                float* __restrict__ out)
{
    __shared__ float w1[NL * NH];     // 8 KB
    __shared__ float w2[NH * NH];     // 16 KB
    __shared__ float w3[NH * NH];     // 16 KB
    __shared__ float bsh[3][NH];
    __shared__ float w4s[NH];

    // unit swizzle: 16 consecutive u (one 64B out-line) on one XCD
    const int bid = blockIdx.x;
    const int u = ((bid & 7) << 4) | (((bid >> 3) & 3) << 7) | (bid >> 5);
    const int t = threadIdx.x;

    // stage weights fp32 (coalesced f4)
    {
        const f4* s1 = (const f4*)(Wd1 + (size_t)u * NL * NH);
        f4* d1 = (f4*)w1;
        for (int i = t; i < NL * NH / 4; i += 256) d1[i] = s1[i];
        const f4* s2 = (const f4*)(Wd2 + (size_t)u * NH * NH);
        f4* d2 = (f4*)w2;
        for (int i = t; i < NH * NH / 4; i += 256) d2[i] = s2[i];
        const f4* s3 = (const f4*)(Wd3 + (size_t)u * NH * NH);
        f4* d3 = (f4*)w3;
        for (int i = t; i < NH * NH / 4; i += 256) d3[i] = s3[i];
        if (t < NH) {
            bsh[0][t] = bd1[(size_t)u * NH + t];
            bsh[1][t] = bd2[(size_t)u * NH + t];
            bsh[2][t] = bd3[(size_t)u * NH + t];
            w4s[t]    = Wd4[(size_t)u * NH + t];
        }
    }
    __syncthreads();

    const int w  = t >> 6;          // wave 0..3
    const int lr = t & 15;          // batch-row lane
    const int lg = (t & 63) >> 4;   // lane group 0..3
    const float b4 = bd4[u];

    // ---- register A-fragments (W^T), single fp16 RNE ----
    u32x4 a1[4], a2[4][2], a3[4][2];
    #pragma unroll
    for (int mt = 0; mt < 4; ++mt) {
        const int c = lr + 16 * mt;
        #pragma unroll
        for (int i = 0; i < 4; ++i)
            a1[mt][i] = pk_rne(w1[(lg * 8 + 2 * i) * NH + c],
                               w1[(lg * 8 + 2 * i + 1) * NH + c]);
        #pragma unroll
        for (int ks = 0; ks < 2; ++ks) {
            #pragma unroll
            for (int i = 0; i < 4; ++i) {
                const int k = ks * 32 + lg * 8 + 2 * i;
                a2[mt][ks][i] = pk_rne(w2[k * NH + c], w2[(k + 1) * NH + c]);
                a3[mt][ks][i] = pk_rne(w3[k * NH + c], w3[(k + 1) * NH + c]);
            }
        }
    }

    // biases as packed bf16 pairs (zeros in this problem; 1-op unpack)
    uint32_t bpk1[4][2], bpk2[4][2], bpk3[4][2];
    #pragma unroll
    for (int mt = 0; mt < 4; ++mt) {
        const int c = 16 * mt + lg * 4;
        bpk1[mt][0] = rpk(bsh[0][c], bsh[0][c + 1]);
        bpk1[mt][1] = rpk(bsh[0][c + 2], bsh[0][c + 3]);
        bpk2[mt][0] = rpk(bsh[1][c], bsh[1][c + 1]);
        bpk2[mt][1] = rpk(bsh[1][c + 2], bsh[1][c + 3]);
        bpk3[mt][0] = rpk(bsh[2][c], bsh[2][c + 1]);
        bpk3[mt][1] = rpk(bsh[2][c + 2], bsh[2][c + 3]);
    }

    // per-lane Wd4 values: cols 16*mt + lg*4 + r
    f4 wd4v[4];
    #pragma unroll
    for (int mt = 0; mt < 4; ++mt)
        wd4v[mt] = *(const f4*)&w4s[16 * mt + lg * 4];

    const int rl = w * 16 + lr;     // block-local row of this lane

    f4 zc0 = *(const f4*)(z + (size_t)rl * NL + lg * 8);
    f4 zc1 = *(const f4*)(z + (size_t)rl * NL + lg * 8 + 4);

    for (int it = 0; it < 32; ++it) {
        const int row = it * 64 + rl;
        const int rnext = ((it + 1) & 31) * 64 + rl;
        f4 zn0 = *(const f4*)(z + (size_t)rnext * NL + lg * 8);
        f4 zn1 = *(const f4*)(z + (size_t)rnext * NL + lg * 8 + 4);

        // ---- L1: B-frag from z ----
        u32x4 bh;
        bh[0] = pk_rtz(zc0[0], zc0[1]);
        bh[1] = pk_rtz(zc0[2], zc0[3]);
        bh[2] = pk_rtz(zc1[0], zc1[1]);
        bh[3] = pk_rtz(zc1[2], zc1[3]);

        f4 acc[4];
        #pragma unroll
        for (int mt = 0; mt < 4; ++mt) {
            acc[mt][0] = __uint_as_float(bpk1[mt][0] << 16);
            acc[mt][1] = __uint_as_float(bpk1[mt][0] & 0xFFFF0000u);
            acc[mt][2] = __uint_as_float(bpk1[mt][1] << 16);
            acc[mt][3] = __uint_as_float(bpk1[mt][1] & 0xFFFF0000u);
            acc[mt] = mfma16h(a1[mt], bh, acc[mt]);
        }

        // relu + pack h1
        uint32_t pk[4][2];
        #pragma unroll
        for (int mt = 0; mt < 4; ++mt) {
            pk[mt][0] = pk_rtz(fmaxf(acc[mt][0], 0.f), fmaxf(acc[mt][1], 0.f));
            pk[mt][1] = pk_rtz(fmaxf(acc[mt][2], 0.f), fmaxf(acc[mt][3], 0.f));
        }

        // ---- L2 ----
        #pragma unroll
        for (int mt = 0; mt < 4; ++mt) {
            acc[mt][0] = __uint_as_float(bpk2[mt][0] << 16);
            acc[mt][1] = __uint_as_float(bpk2[mt][0] & 0xFFFF0000u);
            acc[mt][2] = __uint_as_float(bpk2[mt][1] << 16);
            acc[mt][3] = __uint_as_float(bpk2[mt][1] & 0xFFFF0000u);
        }
        #pragma unroll
        for (int ks = 0; ks < 2; ++ks) {
            u32x4 bf;
            {
                uint32_t b0, b2, b1, b3;
                xch(pk[2 * ks][0], pk[2 * ks + 1][0], b0, b2);
                xch(pk[2 * ks][1], pk[2 * ks + 1][1], b1, b3);
                bf[0] = b0; bf[1] = b1; bf[2] = b2; bf[3] = b3;
            }
            #pragma unroll
            for (int mt = 0; mt < 4; ++mt)
                acc[mt] = mfma16h(a2[mt][ks], bf, acc[mt]);
        }

        // relu + pack h2
        uint32_t pk2[4][2];
        #pragma unroll
        for (int mt = 0; mt < 4; ++mt) {
            pk2[mt][0] = pk_rtz(fmaxf(acc[mt][0], 0.f), fmaxf(acc[mt][1], 0.f));
            pk2[mt][1] = pk_rtz(fmaxf(acc[mt][2], 0.f), fmaxf(acc[mt][3], 0.f));
        }

        // ---- L3 ----
        #pragma unroll
        for (int mt = 0; mt < 4; ++mt) {
            acc[mt][0] = __uint_as_float(bpk3[mt][0] << 16);
            acc[mt][1] = __uint_as_float(bpk3[mt][0] & 0xFFFF0000u);
            acc[mt][2] = __uint_as_float(bpk3[mt][1] << 16);
            acc[mt][3] = __uint_as_float(bpk3[mt][1] & 0xFFFF0000u);
        }
        #pragma unroll
        for (int ks = 0; ks < 2; ++ks) {
            u32x4 bf;
            {
                uint32_t b0, b2, b1, b3;
                xch(pk2[2 * ks][0], pk2[2 * ks + 1][0], b0, b2);
                xch(pk2[2 * ks][1], pk2[2 * ks + 1][1], b1, b3);
                bf[0] = b0; bf[1] = b1; bf[2] = b2; bf[3] = b3;
            }
            #pragma unroll
            for (int mt = 0; mt < 4; ++mt)
                acc[mt] = mfma16h(a3[mt][ks], bf, acc[mt]);
        }

        // ---- L4: fp32 dot with wd4 ----
        float part = 0.f;
        #pragma unroll
        for (int mt = 0; mt < 4; ++mt) {
            part = fmaf(fmaxf(acc[mt][0], 0.f), wd4v[mt][0], part);
            part = fmaf(fmaxf(acc[mt][1], 0.f), wd4v[mt][1], part);
            part = fmaf(fmaxf(acc[mt][2], 0.f), wd4v[mt][2], part);
            part = fmaf(fmaxf(acc[mt][3], 0.f), wd4v[mt][3], part);
        }
        part += __shfl_xor(part, 16);
        part += __shfl_xor(part, 32);
        if ((t & 48) == 0)
            out[(size_t)row * NU + u] = part + b4;

        zc0 = zn0; zc1 = zn1;
    }
}

// ----------------------------------------------------------------- launch ---
extern "C" void kernel_launch(void* const* d_in, const int* in_sizes, int n_in,
                              void* d_out, int out_size, void* d_ws, size_t ws_size,
                              hipStream_t stream)
{
    const float* x   = (const float*)d_in[0];
    const float* We1 = (const float*)d_in[1];
    const float* be1 = (const float*)d_in[2];
    const float* We2 = (const float*)d_in[3];
    const float* be2 = (const float*)d_in[4];
    const float* We3 = (const float*)d_in[5];
    const float* be3 = (const float*)d_in[6];
    const float* We4 = (const float*)d_in[7];
    const float* be4 = (const float*)d_in[8];
    const float* Wd1 = (const float*)d_in[9];
    const float* bd1 = (const float*)d_in[10];
    const float* Wd2 = (const float*)d_in[11];
    const float* bd2 = (const float*)d_in[12];
    const float* Wd3 = (const float*)d_in[13];
    const float* bd3 = (const float*)d_in[14];
    const float* Wd4 = (const float*)d_in[15];
    const float* bd4 = (const float*)d_in[16];
    float* out = (float*)d_out;

    float* zbuf = (float*)d_ws;   // 256 KB scratch

    enc_kernel<<<NB / 8, 256, 0, stream>>>(x, We1, be1, We2, be2, We3, be3,
                                           We4, be4, zbuf);
    dec_kernel<<<NU, 256, 0, stream>>>(zbuf, Wd1, bd1, Wd2, bd2,
                                       Wd3, bd3, Wd4, bd4, out);
}